// Round 1
// baseline (546.721 us; speedup 1.0000x reference)
//
#include <hip/hip_runtime.h>
#include <hip/hip_bf16.h>

typedef __hip_bfloat16 bf16;
typedef short short8 __attribute__((ext_vector_type(8)));
typedef float f32x4 __attribute__((ext_vector_type(4)));

#define Lq 512
#define Sm 2048
#define Bb 4
#define Ee 1024
#define Hh 16
#define FFd 2048
#define HDd 64

static __device__ __forceinline__ float b2f(bf16 x) { return __bfloat162float(x); }
static __device__ __forceinline__ bf16 f2b(float x) { return __float2bfloat16(x); }

static __device__ __forceinline__ void gload16(const void* g, void* l) {
    __builtin_amdgcn_global_load_lds(
        (const __attribute__((address_space(1))) unsigned int*)g,
        (__attribute__((address_space(3))) unsigned int*)l, 16, 0, 0);
}

// ---------------------------------------------------------------------------
// NT bf16 MFMA GEMM: C[m,n] = alpha * sum_k A[m,k]*Bw[n,k] + bias[n]
// A: M x K row-major (lda), Bw: N x K row-major (ldb). Batched over blockIdx.z
// with offsets off = (z/zdiv)*s1 + (z%zdiv)*s2 per operand.
// mode: 0 = f32 out; 1 = bf16 out; 2 = bf16 relu out; 3 = bf16 scatter to
//       vt[(row&3)*1024 + col][512] + (row>>2)   (v-projection transpose)
// ---------------------------------------------------------------------------
template<int BM, int BN>
__global__ __launch_bounds__(256)
void gemm_nt(const bf16* __restrict__ A, const bf16* __restrict__ Bw,
             float* __restrict__ Cf, bf16* __restrict__ Cb,
             const float* __restrict__ bias,
             int K, long lda, long ldb, long ldc,
             long sA1, long sA2, long sB1, long sB2, long sC1, long sC2,
             int zdiv, float alpha, int mode)
{
    constexpr int BK = 32;
    __shared__ bf16 lA[BM * BK];
    __shared__ bf16 lB[BN * BK];

    const int tid  = threadIdx.x;
    const int lane = tid & 63;
    const int wave = tid >> 6;
    const int wm = wave >> 1, wn = wave & 1;
    constexpr int RM = BM / 2, RN = BN / 2;
    constexpr int FM = RM / 16, FN = RN / 16;
    constexpr int RA = BM / 64;   // staging rounds (BM*BK bf16 / (256 lanes * 16B))
    constexpr int RB = BN / 64;

    const int z = blockIdx.z;
    const long offA = (long)(z / zdiv) * sA1 + (long)(z % zdiv) * sA2;
    const long offB = (long)(z / zdiv) * sB1 + (long)(z % zdiv) * sB2;
    const long offC = (long)(z / zdiv) * sC1 + (long)(z % zdiv) * sC2;

    const int m0 = blockIdx.x * BM;
    const int n0 = blockIdx.y * BN;

    const int kgrp = lane >> 4;   // 0..3
    const int l16  = lane & 15;

    f32x4 acc[FM][FN];
#pragma unroll
    for (int i = 0; i < FM; i++)
#pragma unroll
        for (int j = 0; j < FN; j++) acc[i][j] = f32x4{0.f, 0.f, 0.f, 0.f};

    for (int k0 = 0; k0 < K; k0 += BK) {
        __syncthreads();
#pragma unroll
        for (int r = 0; r < RA; r++) {
            int c = r * 256 + wave * 64 + lane;
            int row = c >> 2, kk = (c & 3) * 8;
            const bf16* g = A + offA + (long)(m0 + row) * lda + (k0 + kk);
            gload16(g, &lA[(r * 256 + wave * 64) * 8]);
        }
#pragma unroll
        for (int r = 0; r < RB; r++) {
            int c = r * 256 + wave * 64 + lane;
            int row = c >> 2, kk = (c & 3) * 8;
            const bf16* g = Bw + offB + (long)(n0 + row) * ldb + (k0 + kk);
            gload16(g, &lB[(r * 256 + wave * 64) * 8]);
        }
        asm volatile("s_waitcnt vmcnt(0)" ::: "memory");
        __syncthreads();

        short8 af[FM], bv[FN];
#pragma unroll
        for (int i = 0; i < FM; i++)
            af[i] = *(const short8*)&lA[(wm * RM + i * 16 + l16) * BK + kgrp * 8];
#pragma unroll
        for (int j = 0; j < FN; j++)
            bv[j] = *(const short8*)&lB[(wn * RN + j * 16 + l16) * BK + kgrp * 8];
#pragma unroll
        for (int i = 0; i < FM; i++)
#pragma unroll
            for (int j = 0; j < FN; j++)
                acc[i][j] = __builtin_amdgcn_mfma_f32_16x16x32_bf16(af[i], bv[j], acc[i][j], 0, 0, 0);
    }

#pragma unroll
    for (int i = 0; i < FM; i++) {
#pragma unroll
        for (int j = 0; j < FN; j++) {
#pragma unroll
            for (int r = 0; r < 4; r++) {
                int row = m0 + wm * RM + i * 16 + kgrp * 4 + r;
                int col = n0 + wn * RN + j * 16 + l16;
                float v = alpha * acc[i][j][r] + (bias ? bias[col] : 0.f);
                if (mode == 0) {
                    Cf[offC + (long)row * ldc + col] = v;
                } else if (mode == 1) {
                    Cb[offC + (long)row * ldc + col] = f2b(v);
                } else if (mode == 2) {
                    Cb[offC + (long)row * ldc + col] = f2b(fmaxf(v, 0.f));
                } else {
                    // vt[b=row&3][o=col][m=row>>2],  o-major stride 512
                    Cb[((long)(row & 3) * 1024 + col) * 512 + (row >> 2)] = f2b(v);
                }
            }
        }
    }
}

// ---------------------------------------------------------------------------
// fused f32->bf16 convert (optionally a+b) prepass; segment per blockIdx.y
// ---------------------------------------------------------------------------
struct CvtSeg { const float* a; const float* b; bf16* d; int n; };
struct CvtArgs { CvtSeg s[10]; };

__global__ __launch_bounds__(256)
void cvt_kernel(CvtArgs args)
{
    CvtSeg sg = args.s[blockIdx.y];
    long i = ((long)blockIdx.x * 256 + threadIdx.x) * 4;
    if (i >= sg.n) return;
    float4 av = *(const float4*)(sg.a + i);
    if (sg.b) {
        float4 bvv = *(const float4*)(sg.b + i);
        av.x += bvv.x; av.y += bvv.y; av.z += bvv.z; av.w += bvv.w;
    }
    ushort4 u;
    u.x = __builtin_bit_cast(unsigned short, f2b(av.x));
    u.y = __builtin_bit_cast(unsigned short, f2b(av.y));
    u.z = __builtin_bit_cast(unsigned short, f2b(av.z));
    u.w = __builtin_bit_cast(unsigned short, f2b(av.w));
    *reinterpret_cast<ushort4*>((unsigned short*)sg.d + i) = u;
}

// ---------------------------------------------------------------------------
// self-attn softmax, in-place on bf16 scores rows of length 512 (wave/row)
// ---------------------------------------------------------------------------
__global__ __launch_bounds__(256)
void softmax_self(bf16* __restrict__ p)
{
    long row = (long)blockIdx.x * 4 + (threadIdx.x >> 6);
    int lane = threadIdx.x & 63;
    bf16* base = p + row * 512;
    float v[8];
    float mx = -1e30f;
#pragma unroll
    for (int i = 0; i < 8; i++) { v[i] = b2f(base[lane + i * 64]); mx = fmaxf(mx, v[i]); }
    for (int o = 32; o; o >>= 1) mx = fmaxf(mx, __shfl_xor(mx, o));
    float s = 0.f;
#pragma unroll
    for (int i = 0; i < 8; i++) { v[i] = __expf(v[i] - mx); s += v[i]; }
    for (int o = 32; o; o >>= 1) s += __shfl_xor(s, o);
    float inv = 1.f / s;
#pragma unroll
    for (int i = 0; i < 8; i++) base[lane + i * 64] = f2b(v[i] * inv);
}

// ---------------------------------------------------------------------------
// LayerNorm over E=1024: y = LN(x [+ res] [+ resb(row&3)]) * g + b
// outF (f32) and/or outB (bf16) may be written. One block per row.
// ---------------------------------------------------------------------------
__global__ __launch_bounds__(256)
void ln_kernel(const float* __restrict__ x, const float* __restrict__ res,
               const float* __restrict__ resb,
               const float* __restrict__ g, const float* __restrict__ be,
               float* __restrict__ outF, bf16* __restrict__ outB)
{
    long row = blockIdx.x;
    int tid = threadIdx.x, lane = tid & 63, w = tid >> 6;
    float4 xv = *(const float4*)(x + row * 1024 + tid * 4);
    float vv[4] = {xv.x, xv.y, xv.z, xv.w};
    if (res) {
        float4 rv = *(const float4*)(res + row * 1024 + tid * 4);
        vv[0] += rv.x; vv[1] += rv.y; vv[2] += rv.z; vv[3] += rv.w;
    }
    if (resb) {
        float4 rv = *(const float4*)(resb + (row & 3) * 1024 + tid * 4);
        vv[0] += rv.x; vv[1] += rv.y; vv[2] += rv.z; vv[3] += rv.w;
    }
    float s = vv[0] + vv[1] + vv[2] + vv[3];
    float q = vv[0] * vv[0] + vv[1] * vv[1] + vv[2] * vv[2] + vv[3] * vv[3];
    __shared__ float rs[4], rq[4];
    for (int o = 32; o; o >>= 1) { s += __shfl_xor(s, o); q += __shfl_xor(q, o); }
    if (!lane) { rs[w] = s; rq[w] = q; }
    __syncthreads();
    s = rs[0] + rs[1] + rs[2] + rs[3];
    q = rq[0] + rq[1] + rq[2] + rq[3];
    float mean = s * (1.f / 1024.f);
    float var  = q * (1.f / 1024.f) - mean * mean;
    float rstd = rsqrtf(var + 1e-5f);
    float4 gv = *(const float4*)(g + tid * 4);
    float4 bv = *(const float4*)(be + tid * 4);
    float o0 = (vv[0] - mean) * rstd * gv.x + bv.x;
    float o1 = (vv[1] - mean) * rstd * gv.y + bv.y;
    float o2 = (vv[2] - mean) * rstd * gv.z + bv.z;
    float o3 = (vv[3] - mean) * rstd * gv.w + bv.w;
    if (outF) {
        float4 ov = {o0, o1, o2, o3};
        *(float4*)(outF + row * 1024 + tid * 4) = ov;
    }
    if (outB) {
        ushort4 u;
        u.x = __builtin_bit_cast(unsigned short, f2b(o0));
        u.y = __builtin_bit_cast(unsigned short, f2b(o1));
        u.z = __builtin_bit_cast(unsigned short, f2b(o2));
        u.w = __builtin_bit_cast(unsigned short, f2b(o3));
        *reinterpret_cast<ushort4*>((unsigned short*)outB + row * 1024 + tid * 4) = u;
    }
}

// ---------------------------------------------------------------------------
// asum[b,e] = sum_l (tgt1[(l*4+b),e] + qp[(l*4+b),e])   grid 16x256
// ---------------------------------------------------------------------------
__global__ __launch_bounds__(256)
void asum_kernel(const float* __restrict__ t1, const float* __restrict__ qp,
                 float* __restrict__ asum)
{
    int b = blockIdx.x >> 2, ch = blockIdx.x & 3;
    int e = ch * 256 + threadIdx.x;
    float acc = 0.f;
    for (int l = 0; l < Lq; l++) {
        long idx = ((long)(l * 4 + b)) * 1024 + e;
        acc += t1[idx] + qp[idx];
    }
    asum[b * 1024 + e] = acc;
}

// ---------------------------------------------------------------------------
// qsum[b,o] = sum_e cq_w[o,e]*asum[b,e] + 512*cq_b[o]    one wave per o
// ---------------------------------------------------------------------------
__global__ __launch_bounds__(256)
void qsum_kernel(const float* __restrict__ cqw, const float* __restrict__ cqb,
                 const float* __restrict__ asum, float* __restrict__ qsum)
{
    int o = blockIdx.x * 4 + (threadIdx.x >> 6);
    int lane = threadIdx.x & 63;
    float a0 = 0, a1 = 0, a2 = 0, a3 = 0;
    for (int j = 0; j < 16; j++) {
        int e = lane + j * 64;
        float wv = cqw[(long)o * 1024 + e];
        a0 += wv * asum[e];
        a1 += wv * asum[1024 + e];
        a2 += wv * asum[2048 + e];
        a3 += wv * asum[3072 + e];
    }
    for (int t = 32; t; t >>= 1) {
        a0 += __shfl_xor(a0, t); a1 += __shfl_xor(a1, t);
        a2 += __shfl_xor(a2, t); a3 += __shfl_xor(a3, t);
    }
    if (!lane) {
        float bb = 512.f * cqb[o];
        qsum[o] = a0 + bb; qsum[1024 + o] = a1 + bb;
        qsum[2048 + o] = a2 + bb; qsum[3072 + o] = a3 + bb;
    }
}

// ---------------------------------------------------------------------------
// cross-attention: per (b,h) block.
//  s1[m]   = scale * sum_d qsum[b,d*16+h] * kc[b,(d*16+h),m]
//  wpr[m]  = sum_n down_w[n] * softmax_m(kc[b,(n*16+h),m]*s1[m])
//  out[b,(d*16+h)] = sum_m wpr[m]*vc[b,(d*16+h),m] + down_b
// ---------------------------------------------------------------------------
__global__ __launch_bounds__(256)
void cross_kernel(const float* __restrict__ kc, const bf16* __restrict__ vc,
                  const float* __restrict__ qsum, const float* __restrict__ dw,
                  const float* __restrict__ db, float* __restrict__ outs)
{
    int b = blockIdx.x >> 4, h = blockIdx.x & 15;
    int tid = threadIdx.x, lane = tid & 63, w = tid >> 6;
    __shared__ float qd[64];
    __shared__ float s1m[2048];
    __shared__ float wpr[2048];
    __shared__ float red[4];

    if (tid < 64) qd[tid] = qsum[b * 1024 + tid * 16 + h];
    for (int m = tid; m < 2048; m += 256) wpr[m] = 0.f;
    __syncthreads();

    const float* kcb = kc + (long)b * 1024 * 2048;
    for (int m = tid; m < 2048; m += 256) {
        float acc = 0.f;
#pragma unroll 8
        for (int d = 0; d < 64; d++)
            acc += qd[d] * kcb[(long)(d * 16 + h) * 2048 + m];
        s1m[m] = acc * 0.125f;
    }
    __syncthreads();

    for (int n = 0; n < 64; n++) {
        const float* row = kcb + (long)(n * 16 + h) * 2048;
        float t[8];
        float mx = -1e30f;
#pragma unroll
        for (int i = 0; i < 8; i++) {
            int m = tid + i * 256;
            t[i] = row[m] * s1m[m];
            mx = fmaxf(mx, t[i]);
        }
        for (int o = 32; o; o >>= 1) mx = fmaxf(mx, __shfl_xor(mx, o));
        __syncthreads();
        if (!lane) red[w] = mx;
        __syncthreads();
        mx = fmaxf(fmaxf(red[0], red[1]), fmaxf(red[2], red[3]));
        float s = 0.f;
#pragma unroll
        for (int i = 0; i < 8; i++) { t[i] = __expf(t[i] - mx); s += t[i]; }
        for (int o = 32; o; o >>= 1) s += __shfl_xor(s, o);
        __syncthreads();
        if (!lane) red[w] = s;
        __syncthreads();
        s = red[0] + red[1] + red[2] + red[3];
        float sc = dw[n] / s;
#pragma unroll
        for (int i = 0; i < 8; i++) wpr[tid + i * 256] += t[i] * sc;
    }
    __syncthreads();

    const bf16* vcb = vc + (long)b * 1024 * 2048;
    for (int dd = 0; dd < 16; dd++) {
        int d = w * 16 + dd;
        const bf16* vrow = vcb + (long)(d * 16 + h) * 2048;
        float acc = 0.f;
        for (int j = 0; j < 32; j++) {
            int m = lane + j * 64;
            acc += wpr[m] * b2f(vrow[m]);
        }
        for (int t2 = 32; t2; t2 >>= 1) acc += __shfl_xor(acc, t2);
        if (!lane) outs[b * 1024 + d * 16 + h] = acc + db[0];
    }
}

// ---------------------------------------------------------------------------
extern "C" void kernel_launch(void* const* d_in, const int* in_sizes, int n_in,
                              void* d_out, int out_size, void* d_ws, size_t ws_size,
                              hipStream_t stream)
{
    const float* tgt  = (const float*)d_in[0];
    const float* mem  = (const float*)d_in[1];
    const float* pos  = (const float*)d_in[2];
    const float* qp   = (const float*)d_in[3];
    const float* ipw  = (const float*)d_in[4];
    const float* ipb  = (const float*)d_in[5];
    const float* outw = (const float*)d_in[6];
    const float* outb = (const float*)d_in[7];
    const float* cqw  = (const float*)d_in[8];
    const float* cqb  = (const float*)d_in[9];
    const float* ckw  = (const float*)d_in[10];
    const float* ckb  = (const float*)d_in[11];
    const float* cvw  = (const float*)d_in[12];
    const float* cvb  = (const float*)d_in[13];
    const float* dww  = (const float*)d_in[14];
    const float* dwb  = (const float*)d_in[15];
    const float* l1w  = (const float*)d_in[16];
    const float* l1b  = (const float*)d_in[17];
    const float* l2w  = (const float*)d_in[18];
    const float* l2b  = (const float*)d_in[19];
    const float* n1g  = (const float*)d_in[20];
    const float* n1b  = (const float*)d_in[21];
    const float* n2g  = (const float*)d_in[22];
    const float* n2b  = (const float*)d_in[23];
    const float* n3g  = (const float*)d_in[24];
    const float* n3b  = (const float*)d_in[25];

    char* ws = (char*)d_ws;
    auto MB = [](long x) { return x << 20; };
    bf16* w_ip    = (bf16*)(ws + MB(0));    // 6 MB
    bf16* w_out   = (bf16*)(ws + MB(6));    // 2 MB
    bf16* w_ck    = (bf16*)(ws + MB(8));    // 2 MB
    bf16* w_cv    = (bf16*)(ws + MB(10));   // 2 MB
    bf16* w_l1    = (bf16*)(ws + MB(12));   // 4 MB
    bf16* w_l2    = (bf16*)(ws + MB(16));   // 4 MB
    bf16* qkin    = (bf16*)(ws + MB(20));   // 4 MB  bf16(tgt+qp)
    bf16* tgtb    = (bf16*)(ws + MB(24));   // 4 MB  bf16(tgt)
    bf16* memposb = (bf16*)(ws + MB(28));   // 16 MB bf16(mem+pos)
    bf16* memb    = (bf16*)(ws + MB(44));   // 16 MB bf16(mem)
    bf16* qkbuf   = (bf16*)(ws + MB(60));   // 8 MB  q|k  [2048][2048]
    bf16* vtb     = (bf16*)(ws + MB(68));   // 4 MB  vt[b][o][m]
    bf16* scores  = (bf16*)(ws + MB(72));   // 32 MB [z=64][512][512]
    float* kcf    = (float*)(ws + MB(72));  // 32 MB (reuses scores region)
    bf16* ctxb    = (bf16*)(ws + MB(104));  // 4 MB
    float* atmp   = (float*)(ws + MB(108)); // 8 MB
    float* tgt1   = (float*)(ws + MB(116)); // 8 MB
    float* asum   = (float*)(ws + MB(124)); // 16 KB
    float* qsum   = (float*)(ws + MB(125)); // 16 KB
    bf16* vcb     = (bf16*)(ws + MB(126));  // 16 MB [b][o][m]
    float* outs   = (float*)(ws + MB(142)); // 16 KB
    float* tgt2   = (float*)(ws + MB(143)); // 8 MB
    bf16* tgt2b   = (bf16*)(ws + MB(151));  // 4 MB
    bf16* ff1b    = (bf16*)(ws + MB(155));  // 8 MB [2048][2048]
    float* ff2    = (float*)(ws + MB(163)); // 8 MB   -> total 171 MB

    // --- prepass: all f32->bf16 conversions (+fused adds) ---
    CvtArgs ca{};
    ca.s[0] = {ipw,  nullptr, w_ip,    3072 * 1024};
    ca.s[1] = {outw, nullptr, w_out,   1024 * 1024};
    ca.s[2] = {ckw,  nullptr, w_ck,    1024 * 1024};
    ca.s[3] = {cvw,  nullptr, w_cv,    1024 * 1024};
    ca.s[4] = {l1w,  nullptr, w_l1,    2048 * 1024};
    ca.s[5] = {l2w,  nullptr, w_l2,    2048 * 1024};
    ca.s[6] = {tgt,  qp,      qkin,    2048 * 1024};
    ca.s[7] = {tgt,  nullptr, tgtb,    2048 * 1024};
    ca.s[8] = {mem,  pos,     memposb, 8192 * 1024};
    ca.s[9] = {mem,  nullptr, memb,    8192 * 1024};
    cvt_kernel<<<dim3(8192, 10, 1), 256, 0, stream>>>(ca);

    // --- q,k projection: [2048,1024] x [1024,2048] -> qkbuf bf16 ---
    gemm_nt<128, 128><<<dim3(16, 16, 1), 256, 0, stream>>>(
        qkin, w_ip, nullptr, qkbuf, ipb,
        1024, 1024, 1024, 2048, 0, 0, 0, 0, 0, 0, 1, 1.f, 1);

    // --- v projection -> vt[b][h*64+d][m] (mode 3 scatter) ---
    gemm_nt<128, 128><<<dim3(16, 8, 1), 256, 0, stream>>>(
        tgtb, w_ip + 2048 * 1024, nullptr, vtb, ipb + 2048,
        1024, 1024, 1024, 0, 0, 0, 0, 0, 0, 0, 1, 1.f, 3);

    // --- QK^T: per z=(b*16+h): [512,64]x[64,512] * 0.125 -> scores bf16 ---
    gemm_nt<128, 128><<<dim3(4, 4, 64), 256, 0, stream>>>(
        qkbuf, qkbuf + 1024, nullptr, scores, nullptr,
        64, 8192, 8192, 512,
        2048, 64, 2048, 64, 4194304, 262144, 16, 0.125f, 1);

    // --- softmax over last axis, in place ---
    softmax_self<<<dim3(8192, 1, 1), 256, 0, stream>>>(scores);

    // --- PV: per z: [512,512]x[512,64] -> ctxb[(l*4+b)][h*64+d] bf16 ---
    gemm_nt<128, 64><<<dim3(4, 1, 64), 256, 0, stream>>>(
        scores, vtb, nullptr, ctxb, nullptr,
        512, 512, 512, 4096,
        4194304, 262144, 524288, 32768, 1024, 64, 16, 1.f, 1);

    // --- out projection -> atmp f32 ---
    gemm_nt<128, 128><<<dim3(16, 8, 1), 256, 0, stream>>>(
        ctxb, w_out, atmp, nullptr, outb,
        1024, 1024, 1024, 1024, 0, 0, 0, 0, 0, 0, 1, 1.f, 0);

    // --- LN1: tgt1 = LN(tgt + atmp) ---
    ln_kernel<<<dim3(2048, 1, 1), 256, 0, stream>>>(atmp, tgt, nullptr, n1g, n1b, tgt1, nullptr);

    // --- qc path reduced: asum then qsum ---
    asum_kernel<<<dim3(16, 1, 1), 256, 0, stream>>>(tgt1, qp, asum);
    qsum_kernel<<<dim3(256, 1, 1), 256, 0, stream>>>(cqw, cqb, asum, qsum);

    // --- kc: per b: [1024(o),1024]x[1024,2048(s)] -> kcf f32 [b][o][s] ---
    gemm_nt<128, 128><<<dim3(8, 16, 4), 256, 0, stream>>>(
        w_ck, memposb, kcf, nullptr, ckb,
        1024, 1024, 4096, 2048,
        0, 0, 1024, 0, 2097152, 0, 1, 1.f, 0);

    // --- vc: per b -> vcb bf16 [b][o][s] ---
    gemm_nt<128, 128><<<dim3(8, 16, 4), 256, 0, stream>>>(
        w_cv, memb, nullptr, vcb, cvb,
        1024, 1024, 4096, 2048,
        0, 0, 1024, 0, 2097152, 0, 1, 1.f, 1);

    // --- cross attention + down projection -> outs[b][e] ---
    cross_kernel<<<dim3(64, 1, 1), 256, 0, stream>>>(kcf, vcb, qsum, dww, dwb, outs);

    // --- LN2: tgt2 = LN(tgt1 + outs[b]) (f32 + bf16) ---
    ln_kernel<<<dim3(2048, 1, 1), 256, 0, stream>>>(tgt1, nullptr, outs, n2g, n2b, tgt2, tgt2b);

    // --- FFN ---
    gemm_nt<128, 128><<<dim3(16, 16, 1), 256, 0, stream>>>(
        tgt2b, w_l1, nullptr, ff1b, l1b,
        1024, 1024, 1024, 2048, 0, 0, 0, 0, 0, 0, 1, 1.f, 2);

    gemm_nt<128, 128><<<dim3(16, 8, 1), 256, 0, stream>>>(
        ff1b, w_l2, ff2, nullptr, l2b,
        2048, 2048, 2048, 1024, 0, 0, 0, 0, 0, 0, 1, 1.f, 0);

    // --- LN3 -> d_out f32 ---
    ln_kernel<<<dim3(2048, 1, 1), 256, 0, stream>>>(ff2, tgt2, nullptr, n3g, n3b, (float*)d_out, nullptr);
}

// Round 2
// 458.725 us; speedup vs baseline: 1.1918x; 1.1918x over previous
//
#include <hip/hip_runtime.h>
#include <hip/hip_bf16.h>

typedef __hip_bfloat16 bf16;
typedef short short8 __attribute__((ext_vector_type(8)));
typedef float f32x4 __attribute__((ext_vector_type(4)));

#define Lq 512
#define Sm 2048
#define Bb 4
#define Ee 1024
#define Hh 16
#define FFd 2048
#define HDd 64

static __device__ __forceinline__ float b2f(bf16 x) { return __bfloat162float(x); }
static __device__ __forceinline__ bf16 f2b(float x) { return __float2bfloat16(x); }

static __device__ __forceinline__ void gload16(const void* g, void* l) {
    __builtin_amdgcn_global_load_lds(
        (const __attribute__((address_space(1))) unsigned int*)g,
        (__attribute__((address_space(3))) unsigned int*)l, 16, 0, 0);
}

// ---------------------------------------------------------------------------
// NT bf16 MFMA GEMM: C[m,n] = alpha * sum_k A[m,k]*Bw[n,k] + bias[n]
// ---------------------------------------------------------------------------
template<int BM, int BN>
__global__ __launch_bounds__(256)
void gemm_nt(const bf16* __restrict__ A, const bf16* __restrict__ Bw,
             float* __restrict__ Cf, bf16* __restrict__ Cb,
             const float* __restrict__ bias,
             int K, long lda, long ldb, long ldc,
             long sA1, long sA2, long sB1, long sB2, long sC1, long sC2,
             int zdiv, float alpha, int mode)
{
    constexpr int BK = 32;
    __shared__ bf16 lA[BM * BK];
    __shared__ bf16 lB[BN * BK];

    const int tid  = threadIdx.x;
    const int lane = tid & 63;
    const int wave = tid >> 6;
    const int wm = wave >> 1, wn = wave & 1;
    constexpr int RM = BM / 2, RN = BN / 2;
    constexpr int FM = RM / 16, FN = RN / 16;
    constexpr int RA = BM / 64;
    constexpr int RB = BN / 64;

    const int z = blockIdx.z;
    const long offA = (long)(z / zdiv) * sA1 + (long)(z % zdiv) * sA2;
    const long offB = (long)(z / zdiv) * sB1 + (long)(z % zdiv) * sB2;
    const long offC = (long)(z / zdiv) * sC1 + (long)(z % zdiv) * sC2;

    const int m0 = blockIdx.x * BM;
    const int n0 = blockIdx.y * BN;

    const int kgrp = lane >> 4;
    const int l16  = lane & 15;

    f32x4 acc[FM][FN];
#pragma unroll
    for (int i = 0; i < FM; i++)
#pragma unroll
        for (int j = 0; j < FN; j++) acc[i][j] = f32x4{0.f, 0.f, 0.f, 0.f};

    for (int k0 = 0; k0 < K; k0 += BK) {
        __syncthreads();
#pragma unroll
        for (int r = 0; r < RA; r++) {
            int c = r * 256 + wave * 64 + lane;
            int row = c >> 2, kk = (c & 3) * 8;
            const bf16* g = A + offA + (long)(m0 + row) * lda + (k0 + kk);
            gload16(g, &lA[(r * 256 + wave * 64) * 8]);
        }
#pragma unroll
        for (int r = 0; r < RB; r++) {
            int c = r * 256 + wave * 64 + lane;
            int row = c >> 2, kk = (c & 3) * 8;
            const bf16* g = Bw + offB + (long)(n0 + row) * ldb + (k0 + kk);
            gload16(g, &lB[(r * 256 + wave * 64) * 8]);
        }
        asm volatile("s_waitcnt vmcnt(0)" ::: "memory");
        __syncthreads();

        short8 af[FM], bv[FN];
#pragma unroll
        for (int i = 0; i < FM; i++)
            af[i] = *(const short8*)&lA[(wm * RM + i * 16 + l16) * BK + kgrp * 8];
#pragma unroll
        for (int j = 0; j < FN; j++)
            bv[j] = *(const short8*)&lB[(wn * RN + j * 16 + l16) * BK + kgrp * 8];
#pragma unroll
        for (int i = 0; i < FM; i++)
#pragma unroll
            for (int j = 0; j < FN; j++)
                acc[i][j] = __builtin_amdgcn_mfma_f32_16x16x32_bf16(af[i], bv[j], acc[i][j], 0, 0, 0);
    }

#pragma unroll
    for (int i = 0; i < FM; i++) {
#pragma unroll
        for (int j = 0; j < FN; j++) {
#pragma unroll
            for (int r = 0; r < 4; r++) {
                int row = m0 + wm * RM + i * 16 + kgrp * 4 + r;
                int col = n0 + wn * RN + j * 16 + l16;
                float v = alpha * acc[i][j][r] + (bias ? bias[col] : 0.f);
                if (mode == 0) {
                    Cf[offC + (long)row * ldc + col] = v;
                } else if (mode == 1) {
                    Cb[offC + (long)row * ldc + col] = f2b(v);
                } else if (mode == 2) {
                    Cb[offC + (long)row * ldc + col] = f2b(fmaxf(v, 0.f));
                } else {
                    Cb[((long)(row & 3) * 1024 + col) * 512 + (row >> 2)] = f2b(v);
                }
            }
        }
    }
}

// ---------------------------------------------------------------------------
// fused f32->bf16 convert (optionally a+b) prepass
// ---------------------------------------------------------------------------
struct CvtSeg { const float* a; const float* b; bf16* d; int n; };
struct CvtArgs { CvtSeg s[10]; };

__global__ __launch_bounds__(256)
void cvt_kernel(CvtArgs args)
{
    CvtSeg sg = args.s[blockIdx.y];
    long i = ((long)blockIdx.x * 256 + threadIdx.x) * 4;
    if (i >= sg.n) return;
    float4 av = *(const float4*)(sg.a + i);
    if (sg.b) {
        float4 bvv = *(const float4*)(sg.b + i);
        av.x += bvv.x; av.y += bvv.y; av.z += bvv.z; av.w += bvv.w;
    }
    ushort4 u;
    u.x = __builtin_bit_cast(unsigned short, f2b(av.x));
    u.y = __builtin_bit_cast(unsigned short, f2b(av.y));
    u.z = __builtin_bit_cast(unsigned short, f2b(av.z));
    u.w = __builtin_bit_cast(unsigned short, f2b(av.w));
    *reinterpret_cast<ushort4*>((unsigned short*)sg.d + i) = u;
}

// ---------------------------------------------------------------------------
// self-attn softmax, in-place on bf16 scores rows of length 512 (wave/row)
// ---------------------------------------------------------------------------
__global__ __launch_bounds__(256)
void softmax_self(bf16* __restrict__ p)
{
    long row = (long)blockIdx.x * 4 + (threadIdx.x >> 6);
    int lane = threadIdx.x & 63;
    bf16* base = p + row * 512;
    float v[8];
    float mx = -1e30f;
#pragma unroll
    for (int i = 0; i < 8; i++) { v[i] = b2f(base[lane + i * 64]); mx = fmaxf(mx, v[i]); }
    for (int o = 32; o; o >>= 1) mx = fmaxf(mx, __shfl_xor(mx, o));
    float s = 0.f;
#pragma unroll
    for (int i = 0; i < 8; i++) { v[i] = __expf(v[i] - mx); s += v[i]; }
    for (int o = 32; o; o >>= 1) s += __shfl_xor(s, o);
    float inv = 1.f / s;
#pragma unroll
    for (int i = 0; i < 8; i++) base[lane + i * 64] = f2b(v[i] * inv);
}

// ---------------------------------------------------------------------------
// LayerNorm over E=1024
// ---------------------------------------------------------------------------
__global__ __launch_bounds__(256)
void ln_kernel(const float* __restrict__ x, const float* __restrict__ res,
               const float* __restrict__ resb,
               const float* __restrict__ g, const float* __restrict__ be,
               float* __restrict__ outF, bf16* __restrict__ outB)
{
    long row = blockIdx.x;
    int tid = threadIdx.x, lane = tid & 63, w = tid >> 6;
    float4 xv = *(const float4*)(x + row * 1024 + tid * 4);
    float vv[4] = {xv.x, xv.y, xv.z, xv.w};
    if (res) {
        float4 rv = *(const float4*)(res + row * 1024 + tid * 4);
        vv[0] += rv.x; vv[1] += rv.y; vv[2] += rv.z; vv[3] += rv.w;
    }
    if (resb) {
        float4 rv = *(const float4*)(resb + (row & 3) * 1024 + tid * 4);
        vv[0] += rv.x; vv[1] += rv.y; vv[2] += rv.z; vv[3] += rv.w;
    }
    float s = vv[0] + vv[1] + vv[2] + vv[3];
    float q = vv[0] * vv[0] + vv[1] * vv[1] + vv[2] * vv[2] + vv[3] * vv[3];
    __shared__ float rs[4], rq[4];
    for (int o = 32; o; o >>= 1) { s += __shfl_xor(s, o); q += __shfl_xor(q, o); }
    if (!lane) { rs[w] = s; rq[w] = q; }
    __syncthreads();
    s = rs[0] + rs[1] + rs[2] + rs[3];
    q = rq[0] + rq[1] + rq[2] + rq[3];
    float mean = s * (1.f / 1024.f);
    float var  = q * (1.f / 1024.f) - mean * mean;
    float rstd = rsqrtf(var + 1e-5f);
    float4 gv = *(const float4*)(g + tid * 4);
    float4 bv = *(const float4*)(be + tid * 4);
    float o0 = (vv[0] - mean) * rstd * gv.x + bv.x;
    float o1 = (vv[1] - mean) * rstd * gv.y + bv.y;
    float o2 = (vv[2] - mean) * rstd * gv.z + bv.z;
    float o3 = (vv[3] - mean) * rstd * gv.w + bv.w;
    if (outF) {
        float4 ov = {o0, o1, o2, o3};
        *(float4*)(outF + row * 1024 + tid * 4) = ov;
    }
    if (outB) {
        ushort4 u;
        u.x = __builtin_bit_cast(unsigned short, f2b(o0));
        u.y = __builtin_bit_cast(unsigned short, f2b(o1));
        u.z = __builtin_bit_cast(unsigned short, f2b(o2));
        u.w = __builtin_bit_cast(unsigned short, f2b(o3));
        *reinterpret_cast<ushort4*>((unsigned short*)outB + row * 1024 + tid * 4) = u;
    }
}

// ---------------------------------------------------------------------------
// asum partial: part[(lc*4+b)*1024+e] = sum_{l in lc chunk} (tgt1 + qp)
// grid 256 = lc(16) x b(4) x ec(4)
// ---------------------------------------------------------------------------
__global__ __launch_bounds__(256)
void asum_part_kernel(const float* __restrict__ t1, const float* __restrict__ qp,
                      float* __restrict__ part)
{
    int blk = blockIdx.x;
    int lc = blk >> 4, b = (blk >> 2) & 3, ec = blk & 3;
    int e = ec * 256 + threadIdx.x;
    float acc = 0.f;
#pragma unroll 4
    for (int l = lc * 32; l < lc * 32 + 32; l++) {
        long idx = ((long)(l * 4 + b)) * 1024 + e;
        acc += t1[idx] + qp[idx];
    }
    part[(lc * 4 + b) * 1024 + e] = acc;
}

__global__ __launch_bounds__(256)
void asum_reduce_kernel(const float* __restrict__ part, float* __restrict__ asum)
{
    int b = blockIdx.x >> 2, ec = blockIdx.x & 3;
    int e = ec * 256 + threadIdx.x;
    float acc = 0.f;
#pragma unroll
    for (int lc = 0; lc < 16; lc++) acc += part[(lc * 4 + b) * 1024 + e];
    asum[b * 1024 + e] = acc;
}

// ---------------------------------------------------------------------------
// qsum[b,o] = sum_e cq_w[o,e]*asum[b,e] + 512*cq_b[o]
// ---------------------------------------------------------------------------
__global__ __launch_bounds__(256)
void qsum_kernel(const float* __restrict__ cqw, const float* __restrict__ cqb,
                 const float* __restrict__ asum, float* __restrict__ qsum)
{
    int o = blockIdx.x * 4 + (threadIdx.x >> 6);
    int lane = threadIdx.x & 63;
    float a0 = 0, a1 = 0, a2 = 0, a3 = 0;
    for (int j = 0; j < 16; j++) {
        int e = lane + j * 64;
        float wv = cqw[(long)o * 1024 + e];
        a0 += wv * asum[e];
        a1 += wv * asum[1024 + e];
        a2 += wv * asum[2048 + e];
        a3 += wv * asum[3072 + e];
    }
    for (int t = 32; t; t >>= 1) {
        a0 += __shfl_xor(a0, t); a1 += __shfl_xor(a1, t);
        a2 += __shfl_xor(a2, t); a3 += __shfl_xor(a3, t);
    }
    if (!lane) {
        float bb = 512.f * cqb[o];
        qsum[o] = a0 + bb; qsum[1024 + o] = a1 + bb;
        qsum[2048 + o] = a2 + bb; qsum[3072 + o] = a3 + bb;
    }
}

// ---------------------------------------------------------------------------
// cross stage A: s1[bh][m] = 0.125 * sum_d qsum[b, d*16+h] * kc[b, d*16+h, m]
// grid (64 bh, 8 mc)
// ---------------------------------------------------------------------------
__global__ __launch_bounds__(256)
void s1_kernel(const float* __restrict__ kc, const float* __restrict__ qsum,
               float* __restrict__ s1)
{
    int bh = blockIdx.x, b = bh >> 4, h = bh & 15;
    int m = blockIdx.y * 256 + threadIdx.x;
    __shared__ float qd[64];
    if (threadIdx.x < 64) qd[threadIdx.x] = qsum[b * 1024 + threadIdx.x * 16 + h];
    __syncthreads();
    const float* kcb = kc + (long)b * 2048 * 1024 + (long)h * 2048 + m;
    float acc = 0.f;
#pragma unroll 8
    for (int d = 0; d < 64; d++) acc += qd[d] * kcb[(long)d * 16 * 2048];
    s1[(long)bh * 2048 + m] = acc * 0.125f;
}

// ---------------------------------------------------------------------------
// cross stage B: per (b,h,n) row: max & expsum of kc[n_row,m]*s1[m]
// grid 4096 = bh(64) x n(64)
// ---------------------------------------------------------------------------
__global__ __launch_bounds__(256)
void bsum_kernel(const float* __restrict__ kc, const float* __restrict__ s1,
                 float* __restrict__ rmax, float* __restrict__ rsum)
{
    int bh = blockIdx.x >> 6, n = blockIdx.x & 63;
    int b = bh >> 4, h = bh & 15;
    int tid = threadIdx.x, lane = tid & 63, w = tid >> 6;
    const float* row = kc + (long)b * 2048 * 1024 + (long)(n * 16 + h) * 2048;
    const float* s1r = s1 + (long)bh * 2048;
    float t[8];
    float mx = -1e30f;
#pragma unroll
    for (int i = 0; i < 8; i++) {
        int m = tid + i * 256;
        t[i] = row[m] * s1r[m];
        mx = fmaxf(mx, t[i]);
    }
    __shared__ float redm[4], reds[4];
    for (int o = 32; o; o >>= 1) mx = fmaxf(mx, __shfl_xor(mx, o));
    if (!lane) redm[w] = mx;
    __syncthreads();
    mx = fmaxf(fmaxf(redm[0], redm[1]), fmaxf(redm[2], redm[3]));
    float s = 0.f;
#pragma unroll
    for (int i = 0; i < 8; i++) s += __expf(t[i] - mx);
    for (int o = 32; o; o >>= 1) s += __shfl_xor(s, o);
    if (!lane) reds[w] = s;
    __syncthreads();
    if (!tid) {
        rmax[bh * 64 + n] = mx;
        rsum[bh * 64 + n] = reds[0] + reds[1] + reds[2] + reds[3];
    }
}

// ---------------------------------------------------------------------------
// cross stage C: wpr[bh][m] = sum_n (dw[n]/rsum[n]) * exp(kc[n_row,m]*s1[m]-rmax[n])
// grid (64 bh, 8 mc)
// ---------------------------------------------------------------------------
__global__ __launch_bounds__(256)
void wpr_kernel(const float* __restrict__ kc, const float* __restrict__ s1,
                const float* __restrict__ rmax, const float* __restrict__ rsum,
                const float* __restrict__ dw, float* __restrict__ wpr)
{
    int bh = blockIdx.x, b = bh >> 4, h = bh & 15;
    int m = blockIdx.y * 256 + threadIdx.x;
    __shared__ float cf[64], cm[64];
    if (threadIdx.x < 64) {
        cf[threadIdx.x] = dw[threadIdx.x] / rsum[bh * 64 + threadIdx.x];
        cm[threadIdx.x] = rmax[bh * 64 + threadIdx.x];
    }
    __syncthreads();
    float s1v = s1[(long)bh * 2048 + m];
    const float* kcb = kc + (long)b * 2048 * 1024 + (long)h * 2048 + m;
    float acc = 0.f;
#pragma unroll 8
    for (int n = 0; n < 64; n++)
        acc += cf[n] * __expf(kcb[(long)n * 16 * 2048] * s1v - cm[n]);
    wpr[(long)bh * 2048 + m] = acc;
}

// ---------------------------------------------------------------------------
// cross stage D: outs[b, d*16+h] = sum_m wpr[bh][m]*vc[b, d*16+h, m] + db
// grid 256 = bh(64) x dg(4); block: wpr in LDS, wave w does d = dg*16+w*4..+3
// ---------------------------------------------------------------------------
__global__ __launch_bounds__(256)
void cout_kernel(const bf16* __restrict__ vc, const float* __restrict__ wpr,
                 const float* __restrict__ db, float* __restrict__ outs)
{
    int bh = blockIdx.x >> 2, dg = blockIdx.x & 3;
    int b = bh >> 4, h = bh & 15;
    int tid = threadIdx.x, lane = tid & 63, w = tid >> 6;
    __shared__ float lwpr[2048];
#pragma unroll
    for (int i = 0; i < 8; i++) lwpr[tid + i * 256] = wpr[(long)bh * 2048 + tid + i * 256];
    __syncthreads();
#pragma unroll
    for (int dd = 0; dd < 4; dd++) {
        int d = dg * 16 + w * 4 + dd;
        int o = d * 16 + h;
        const bf16* vrow = vc + (long)b * 2048 * 1024 + (long)o * 2048;
        float acc = 0.f;
#pragma unroll
        for (int j = 0; j < 4; j++) {
            int m = j * 512 + lane * 8;
            short8 vv = *(const short8*)&vrow[m];
#pragma unroll
            for (int k = 0; k < 8; k++) {
                bf16 bb = __builtin_bit_cast(bf16, (unsigned short)vv[k]);
                acc += lwpr[m + k] * b2f(bb);
            }
        }
        for (int t2 = 32; t2; t2 >>= 1) acc += __shfl_xor(acc, t2);
        if (!lane) outs[b * 1024 + o] = acc + db[0];
    }
}

// ---------------------------------------------------------------------------
extern "C" void kernel_launch(void* const* d_in, const int* in_sizes, int n_in,
                              void* d_out, int out_size, void* d_ws, size_t ws_size,
                              hipStream_t stream)
{
    const float* tgt  = (const float*)d_in[0];
    const float* mem  = (const float*)d_in[1];
    const float* pos  = (const float*)d_in[2];
    const float* qp   = (const float*)d_in[3];
    const float* ipw  = (const float*)d_in[4];
    const float* ipb  = (const float*)d_in[5];
    const float* outw = (const float*)d_in[6];
    const float* outb = (const float*)d_in[7];
    const float* cqw  = (const float*)d_in[8];
    const float* cqb  = (const float*)d_in[9];
    const float* ckw  = (const float*)d_in[10];
    const float* ckb  = (const float*)d_in[11];
    const float* cvw  = (const float*)d_in[12];
    const float* cvb  = (const float*)d_in[13];
    const float* dww  = (const float*)d_in[14];
    const float* dwb  = (const float*)d_in[15];
    const float* l1w  = (const float*)d_in[16];
    const float* l1b  = (const float*)d_in[17];
    const float* l2w  = (const float*)d_in[18];
    const float* l2b  = (const float*)d_in[19];
    const float* n1g  = (const float*)d_in[20];
    const float* n1b  = (const float*)d_in[21];
    const float* n2g  = (const float*)d_in[22];
    const float* n2b  = (const float*)d_in[23];
    const float* n3g  = (const float*)d_in[24];
    const float* n3b  = (const float*)d_in[25];

    char* ws = (char*)d_ws;
    auto MB = [](long x) { return x << 20; };
    bf16* w_ip    = (bf16*)(ws + MB(0));    // 6 MB
    bf16* w_out   = (bf16*)(ws + MB(6));    // 2 MB
    bf16* w_ck    = (bf16*)(ws + MB(8));    // 2 MB
    bf16* w_cv    = (bf16*)(ws + MB(10));   // 2 MB
    bf16* w_l1    = (bf16*)(ws + MB(12));   // 4 MB
    bf16* w_l2    = (bf16*)(ws + MB(16));   // 4 MB
    bf16* qkin    = (bf16*)(ws + MB(20));   // 4 MB
    bf16* tgtb    = (bf16*)(ws + MB(24));   // 4 MB
    bf16* memposb = (bf16*)(ws + MB(28));   // 16 MB
    bf16* memb    = (bf16*)(ws + MB(44));   // 16 MB
    bf16* qkbuf   = (bf16*)(ws + MB(60));   // 8 MB
    bf16* vtb     = (bf16*)(ws + MB(68));   // 4 MB
    bf16* scores  = (bf16*)(ws + MB(72));   // 32 MB
    float* kcf    = (float*)(ws + MB(72));  // 32 MB (reuses scores region)
    bf16* ctxb    = (bf16*)(ws + MB(104));  // 4 MB
    // atmp slot (MB 108..116) is dead after LN1 -> reused for cross scratch
    float* atmp   = (float*)(ws + MB(108)); // 8 MB (LN1 input)
    float* s1buf  = (float*)(ws + MB(108)); // 512 KB  (after LN1)
    float* wprbuf = (float*)(ws + MB(109)); // 512 KB
    float* rmax   = (float*)(ws + MB(110));             // 16 KB
    float* rsum   = (float*)(ws + MB(110) + (64 << 10)); // 16 KB
    float* part   = (float*)(ws + MB(111)); // 256 KB
    float* tgt1   = (float*)(ws + MB(116)); // 8 MB
    float* asum   = (float*)(ws + MB(124)); // 16 KB
    float* qsum   = (float*)(ws + MB(125)); // 16 KB
    bf16* vcb     = (bf16*)(ws + MB(126));  // 16 MB
    float* outs   = (float*)(ws + MB(142)); // 16 KB
    float* tgt2   = (float*)(ws + MB(143)); // 8 MB
    bf16* tgt2b   = (bf16*)(ws + MB(151));  // 4 MB
    bf16* ff1b    = (bf16*)(ws + MB(155));  // 8 MB
    float* ff2    = (float*)(ws + MB(163)); // 8 MB  -> total 171 MB

    // --- prepass: all f32->bf16 conversions (+fused adds) ---
    CvtArgs ca{};
    ca.s[0] = {ipw,  nullptr, w_ip,    3072 * 1024};
    ca.s[1] = {outw, nullptr, w_out,   1024 * 1024};
    ca.s[2] = {ckw,  nullptr, w_ck,    1024 * 1024};
    ca.s[3] = {cvw,  nullptr, w_cv,    1024 * 1024};
    ca.s[4] = {l1w,  nullptr, w_l1,    2048 * 1024};
    ca.s[5] = {l2w,  nullptr, w_l2,    2048 * 1024};
    ca.s[6] = {tgt,  qp,      qkin,    2048 * 1024};
    ca.s[7] = {tgt,  nullptr, tgtb,    2048 * 1024};
    ca.s[8] = {mem,  pos,     memposb, 8192 * 1024};
    ca.s[9] = {mem,  nullptr, memb,    8192 * 1024};
    cvt_kernel<<<dim3(8192, 10, 1), 256, 0, stream>>>(ca);

    // --- q,k projection ---
    gemm_nt<128, 128><<<dim3(16, 16, 1), 256, 0, stream>>>(
        qkin, w_ip, nullptr, qkbuf, ipb,
        1024, 1024, 1024, 2048, 0, 0, 0, 0, 0, 0, 1, 1.f, 1);

    // --- v projection -> vt[b][o][m] ---
    gemm_nt<128, 128><<<dim3(16, 8, 1), 256, 0, stream>>>(
        tgtb, w_ip + 2048 * 1024, nullptr, vtb, ipb + 2048,
        1024, 1024, 1024, 0, 0, 0, 0, 0, 0, 0, 1, 1.f, 3);

    // --- QK^T ---
    gemm_nt<128, 128><<<dim3(4, 4, 64), 256, 0, stream>>>(
        qkbuf, qkbuf + 1024, nullptr, scores, nullptr,
        64, 8192, 8192, 512,
        2048, 64, 2048, 64, 4194304, 262144, 16, 0.125f, 1);

    softmax_self<<<dim3(8192, 1, 1), 256, 0, stream>>>(scores);

    // --- PV ---
    gemm_nt<128, 64><<<dim3(4, 1, 64), 256, 0, stream>>>(
        scores, vtb, nullptr, ctxb, nullptr,
        512, 512, 512, 4096,
        4194304, 262144, 524288, 32768, 1024, 64, 16, 1.f, 1);

    // --- out projection ---
    gemm_nt<128, 128><<<dim3(16, 8, 1), 256, 0, stream>>>(
        ctxb, w_out, atmp, nullptr, outb,
        1024, 1024, 1024, 1024, 0, 0, 0, 0, 0, 0, 1, 1.f, 0);

    // --- LN1 ---
    ln_kernel<<<dim3(2048, 1, 1), 256, 0, stream>>>(atmp, tgt, nullptr, n1g, n1b, tgt1, nullptr);

    // --- qc path ---
    asum_part_kernel<<<dim3(256, 1, 1), 256, 0, stream>>>(tgt1, qp, part);
    asum_reduce_kernel<<<dim3(16, 1, 1), 256, 0, stream>>>(part, asum);
    qsum_kernel<<<dim3(256, 1, 1), 256, 0, stream>>>(cqw, cqb, asum, qsum);

    // --- kc / vc GEMMs ---
    gemm_nt<128, 128><<<dim3(8, 16, 4), 256, 0, stream>>>(
        w_ck, memposb, kcf, nullptr, ckb,
        1024, 1024, 4096, 2048,
        0, 0, 1024, 0, 2097152, 0, 1, 1.f, 0);

    gemm_nt<128, 128><<<dim3(8, 16, 4), 256, 0, stream>>>(
        w_cv, memb, nullptr, vcb, cvb,
        1024, 1024, 4096, 2048,
        0, 0, 1024, 0, 2097152, 0, 1, 1.f, 1);

    // --- cross attention, parallel stages ---
    s1_kernel<<<dim3(64, 8, 1), 256, 0, stream>>>(kcf, qsum, s1buf);
    bsum_kernel<<<dim3(4096, 1, 1), 256, 0, stream>>>(kcf, s1buf, rmax, rsum);
    wpr_kernel<<<dim3(64, 8, 1), 256, 0, stream>>>(kcf, s1buf, rmax, rsum, dww, wprbuf);
    cout_kernel<<<dim3(256, 1, 1), 256, 0, stream>>>(vcb, wprbuf, dwb, outs);

    // --- LN2 ---
    ln_kernel<<<dim3(2048, 1, 1), 256, 0, stream>>>(tgt1, nullptr, outs, n2g, n2b, tgt2, tgt2b);

    // --- FFN ---
    gemm_nt<128, 128><<<dim3(16, 16, 1), 256, 0, stream>>>(
        tgt2b, w_l1, nullptr, ff1b, l1b,
        1024, 1024, 1024, 2048, 0, 0, 0, 0, 0, 0, 1, 1.f, 2);

    gemm_nt<128, 128><<<dim3(16, 8, 1), 256, 0, stream>>>(
        ff1b, w_l2, ff2, nullptr, l2b,
        2048, 2048, 2048, 1024, 0, 0, 0, 0, 0, 0, 1, 1.f, 0);

    // --- LN3 -> d_out ---
    ln_kernel<<<dim3(2048, 1, 1), 256, 0, stream>>>(ff2, tgt2, nullptr, n3g, n3b, (float*)d_out, nullptr);
}

// Round 3
// 378.043 us; speedup vs baseline: 1.4462x; 1.2134x over previous
//
#include <hip/hip_runtime.h>
#include <hip/hip_bf16.h>

typedef __hip_bfloat16 bf16;
typedef short short8 __attribute__((ext_vector_type(8)));
typedef float f32x4 __attribute__((ext_vector_type(4)));

#define Lq 512
#define Sm 2048
#define Bb 4
#define Ee 1024
#define Hh 16
#define FFd 2048
#define HDd 64

static __device__ __forceinline__ float b2f(bf16 x) { return __bfloat162float(x); }
static __device__ __forceinline__ bf16 f2b(float x) { return __float2bfloat16(x); }

static __device__ __forceinline__ void gload16(const void* g, void* l) {
    __builtin_amdgcn_global_load_lds(
        (const __attribute__((address_space(1))) unsigned int*)g,
        (__attribute__((address_space(3))) unsigned int*)l, 16, 0, 0);
}

// ---------------------------------------------------------------------------
// NT bf16 MFMA GEMM with 2-deep prefetch (3 LDS buffers, counted vmcnt).
// C[m,n] = alpha * sum_k A[m,k]*Bw[n,k] + bias[n]
// Batched over blockIdx.z: off = (zz/zdiv)*s1 + (zz%zdiv)*s2.
// Operand set 2 (A2/B2/bias2/mode2) selected when z>=zsplit (zz=z-zsplit)
// or n0>=nsplit.
// mode: 0 = f32 out; 1 = bf16 out; 2 = bf16 relu; 3 = bf16 scatter to
//       Cb2[((row&3)*1024 + (col-nsplit))*512 + (row>>2)]  (v-proj transpose)
// ---------------------------------------------------------------------------
template<int BM, int BN>
__global__ __launch_bounds__(256)
void gemm_nt(const bf16* __restrict__ A, const bf16* __restrict__ Bw,
             float* __restrict__ Cf, bf16* __restrict__ Cb,
             const float* __restrict__ bias,
             const bf16* __restrict__ A2, const bf16* __restrict__ B2,
             bf16* __restrict__ Cb2, const float* __restrict__ bias2,
             int K, long lda, long ldb, long ldc,
             long sA1, long sA2, long sB1, long sB2, long sC1, long sC2,
             int zdiv, int zsplit, int nsplit, float alpha, int mode, int mode2)
{
    constexpr int BK = 32;
    constexpr int RA = BM / 64, RB = BN / 64;
    constexpr int NLOADS = RA + RB;     // global_load_lds per wave per stage
    __shared__ bf16 lA[3][BM * BK];
    __shared__ bf16 lB[3][BN * BK];

    const int tid  = threadIdx.x;
    const int lane = tid & 63;
    const int wave = tid >> 6;
    const int wm = wave >> 1, wn = wave & 1;
    constexpr int RM = BM / 2, RN = BN / 2;
    constexpr int FM = RM / 16, FN = RN / 16;

    const int m0 = blockIdx.x * BM;
    const int n0 = blockIdx.y * BN;
    const int z  = blockIdx.z;

    const bool use2 = (z >= zsplit) || (n0 >= nsplit);
    const int  zz   = (z >= zsplit) ? z - zsplit : z;
    const bf16*  Ap = (use2 && A2)    ? A2    : A;
    const bf16*  Bp = (use2 && B2)    ? B2    : Bw;
    const float* bp = (use2 && bias2) ? bias2 : bias;
    const int    md = use2 ? mode2 : mode;

    const long offA = (long)(zz / zdiv) * sA1 + (long)(zz % zdiv) * sA2;
    const long offB = (long)(zz / zdiv) * sB1 + (long)(zz % zdiv) * sB2;
    const long offC = (long)(zz / zdiv) * sC1 + (long)(zz % zdiv) * sC2;

    const bf16* Abase = Ap + offA + (long)m0 * lda;
    const bf16* Bbase = Bp + offB + (long)n0 * ldb;

    const int kgrp = lane >> 4;
    const int l16  = lane & 15;

    auto stage = [&](int buf, int k0) {
#pragma unroll
        for (int r = 0; r < RA; r++) {
            int c = r * 256 + wave * 64 + lane;
            gload16(Abase + (long)(c >> 2) * lda + k0 + (c & 3) * 8,
                    &lA[buf][(r * 256 + wave * 64) * 8]);
        }
#pragma unroll
        for (int r = 0; r < RB; r++) {
            int c = r * 256 + wave * 64 + lane;
            gload16(Bbase + (long)(c >> 2) * ldb + k0 + (c & 3) * 8,
                    &lB[buf][(r * 256 + wave * 64) * 8]);
        }
    };

    f32x4 acc[FM][FN];
#pragma unroll
    for (int i = 0; i < FM; i++)
#pragma unroll
        for (int j = 0; j < FN; j++) acc[i][j] = f32x4{0.f, 0.f, 0.f, 0.f};

    const int nt = K / BK;
    stage(0, 0);
    if (nt > 1) {
        stage(1, BK);
        asm volatile("s_waitcnt vmcnt(%0)" :: "n"(NLOADS) : "memory");
    } else {
        asm volatile("s_waitcnt vmcnt(0)" ::: "memory");
    }
    __builtin_amdgcn_s_barrier();

    for (int t = 0; t < nt; t++) {
        const int cur = t % 3;
        if (t + 2 < nt) stage((t + 2) % 3, (t + 2) * BK);

        short8 af[FM], bv[FN];
#pragma unroll
        for (int i = 0; i < FM; i++)
            af[i] = *(const short8*)&lA[cur][(wm * RM + i * 16 + l16) * BK + kgrp * 8];
#pragma unroll
        for (int j = 0; j < FN; j++)
            bv[j] = *(const short8*)&lB[cur][(wn * RN + j * 16 + l16) * BK + kgrp * 8];
#pragma unroll
        for (int i = 0; i < FM; i++)
#pragma unroll
            for (int j = 0; j < FN; j++)
                acc[i][j] = __builtin_amdgcn_mfma_f32_16x16x32_bf16(af[i], bv[j], acc[i][j], 0, 0, 0);

        if (t + 2 < nt) {
            asm volatile("s_waitcnt vmcnt(%0)" :: "n"(NLOADS) : "memory");
        } else {
            asm volatile("s_waitcnt vmcnt(0)" ::: "memory");
        }
        __builtin_amdgcn_s_barrier();
    }

#pragma unroll
    for (int i = 0; i < FM; i++) {
#pragma unroll
        for (int j = 0; j < FN; j++) {
#pragma unroll
            for (int r = 0; r < 4; r++) {
                int row = m0 + wm * RM + i * 16 + kgrp * 4 + r;
                int col = n0 + wn * RN + j * 16 + l16;
                float v = alpha * acc[i][j][r] + (bp ? bp[col] : 0.f);
                if (md == 0) {
                    Cf[offC + (long)row * ldc + col] = v;
                } else if (md == 1) {
                    Cb[offC + (long)row * ldc + col] = f2b(v);
                } else if (md == 2) {
                    Cb[offC + (long)row * ldc + col] = f2b(fmaxf(v, 0.f));
                } else {
                    int o = col - nsplit;
                    Cb2[((long)(row & 3) * 1024 + o) * 512 + (row >> 2)] = f2b(v);
                }
            }
        }
    }
}

// ---------------------------------------------------------------------------
// f32->bf16 convert prepass, deduped: each segment read once, up to two
// outputs (d = cvt(a[+b]), d2 = cvt(a)). 1D grid, exact block counts.
// ---------------------------------------------------------------------------
struct Cvt2Seg { const float* a; const float* b; bf16* d; bf16* d2; int nblk; };
struct Cvt2Args { Cvt2Seg s[8]; };

__global__ __launch_bounds__(256)
void cvt_kernel(Cvt2Args args)
{
    int bid = blockIdx.x;
    int si = 0;
    while (si < 7 && bid >= args.s[si].nblk) { bid -= args.s[si].nblk; si++; }
    Cvt2Seg sg = args.s[si];
    long i = ((long)bid * 256 + threadIdx.x) * 8;
    float4 a0 = *(const float4*)(sg.a + i);
    float4 a1 = *(const float4*)(sg.a + i + 4);
    float4 s0 = a0, s1 = a1;
    if (sg.b) {
        float4 b0 = *(const float4*)(sg.b + i);
        float4 b1 = *(const float4*)(sg.b + i + 4);
        s0.x += b0.x; s0.y += b0.y; s0.z += b0.z; s0.w += b0.w;
        s1.x += b1.x; s1.y += b1.y; s1.z += b1.z; s1.w += b1.w;
    }
    short8 u;
    u[0] = (short)__builtin_bit_cast(unsigned short, f2b(s0.x));
    u[1] = (short)__builtin_bit_cast(unsigned short, f2b(s0.y));
    u[2] = (short)__builtin_bit_cast(unsigned short, f2b(s0.z));
    u[3] = (short)__builtin_bit_cast(unsigned short, f2b(s0.w));
    u[4] = (short)__builtin_bit_cast(unsigned short, f2b(s1.x));
    u[5] = (short)__builtin_bit_cast(unsigned short, f2b(s1.y));
    u[6] = (short)__builtin_bit_cast(unsigned short, f2b(s1.z));
    u[7] = (short)__builtin_bit_cast(unsigned short, f2b(s1.w));
    *(short8*)((unsigned short*)sg.d + i) = u;
    if (sg.d2) {
        short8 w;
        w[0] = (short)__builtin_bit_cast(unsigned short, f2b(a0.x));
        w[1] = (short)__builtin_bit_cast(unsigned short, f2b(a0.y));
        w[2] = (short)__builtin_bit_cast(unsigned short, f2b(a0.z));
        w[3] = (short)__builtin_bit_cast(unsigned short, f2b(a0.w));
        w[4] = (short)__builtin_bit_cast(unsigned short, f2b(a1.x));
        w[5] = (short)__builtin_bit_cast(unsigned short, f2b(a1.y));
        w[6] = (short)__builtin_bit_cast(unsigned short, f2b(a1.z));
        w[7] = (short)__builtin_bit_cast(unsigned short, f2b(a1.w));
        *(short8*)((unsigned short*)sg.d2 + i) = w;
    }
}

// ---------------------------------------------------------------------------
// self-attn softmax, in-place on bf16 scores rows of length 512 (wave/row)
// ---------------------------------------------------------------------------
__global__ __launch_bounds__(256)
void softmax_self(bf16* __restrict__ p)
{
    long row = (long)blockIdx.x * 4 + (threadIdx.x >> 6);
    int lane = threadIdx.x & 63;
    bf16* base = p + row * 512;
    float v[8];
    float mx = -1e30f;
#pragma unroll
    for (int i = 0; i < 8; i++) { v[i] = b2f(base[lane + i * 64]); mx = fmaxf(mx, v[i]); }
    for (int o = 32; o; o >>= 1) mx = fmaxf(mx, __shfl_xor(mx, o));
    float s = 0.f;
#pragma unroll
    for (int i = 0; i < 8; i++) { v[i] = __expf(v[i] - mx); s += v[i]; }
    for (int o = 32; o; o >>= 1) s += __shfl_xor(s, o);
    float inv = 1.f / s;
#pragma unroll
    for (int i = 0; i < 8; i++) base[lane + i * 64] = f2b(v[i] * inv);
}

// ---------------------------------------------------------------------------
// LayerNorm over E=1024
// ---------------------------------------------------------------------------
__global__ __launch_bounds__(256)
void ln_kernel(const float* __restrict__ x, const float* __restrict__ res,
               const float* __restrict__ resb,
               const float* __restrict__ g, const float* __restrict__ be,
               float* __restrict__ outF, bf16* __restrict__ outB)
{
    long row = blockIdx.x;
    int tid = threadIdx.x, lane = tid & 63, w = tid >> 6;
    float4 xv = *(const float4*)(x + row * 1024 + tid * 4);
    float vv[4] = {xv.x, xv.y, xv.z, xv.w};
    if (res) {
        float4 rv = *(const float4*)(res + row * 1024 + tid * 4);
        vv[0] += rv.x; vv[1] += rv.y; vv[2] += rv.z; vv[3] += rv.w;
    }
    if (resb) {
        float4 rv = *(const float4*)(resb + (row & 3) * 1024 + tid * 4);
        vv[0] += rv.x; vv[1] += rv.y; vv[2] += rv.z; vv[3] += rv.w;
    }
    float s = vv[0] + vv[1] + vv[2] + vv[3];
    float q = vv[0] * vv[0] + vv[1] * vv[1] + vv[2] * vv[2] + vv[3] * vv[3];
    __shared__ float rs[4], rq[4];
    for (int o = 32; o; o >>= 1) { s += __shfl_xor(s, o); q += __shfl_xor(q, o); }
    if (!lane) { rs[w] = s; rq[w] = q; }
    __syncthreads();
    s = rs[0] + rs[1] + rs[2] + rs[3];
    q = rq[0] + rq[1] + rq[2] + rq[3];
    float mean = s * (1.f / 1024.f);
    float var  = q * (1.f / 1024.f) - mean * mean;
    float rstd = rsqrtf(var + 1e-5f);
    float4 gv = *(const float4*)(g + tid * 4);
    float4 bv = *(const float4*)(be + tid * 4);
    float o0 = (vv[0] - mean) * rstd * gv.x + bv.x;
    float o1 = (vv[1] - mean) * rstd * gv.y + bv.y;
    float o2 = (vv[2] - mean) * rstd * gv.z + bv.z;
    float o3 = (vv[3] - mean) * rstd * gv.w + bv.w;
    if (outF) {
        float4 ov = {o0, o1, o2, o3};
        *(float4*)(outF + row * 1024 + tid * 4) = ov;
    }
    if (outB) {
        ushort4 u;
        u.x = __builtin_bit_cast(unsigned short, f2b(o0));
        u.y = __builtin_bit_cast(unsigned short, f2b(o1));
        u.z = __builtin_bit_cast(unsigned short, f2b(o2));
        u.w = __builtin_bit_cast(unsigned short, f2b(o3));
        *reinterpret_cast<ushort4*>((unsigned short*)outB + row * 1024 + tid * 4) = u;
    }
}

// ---------------------------------------------------------------------------
// asum partials over L, then reduce
// ---------------------------------------------------------------------------
__global__ __launch_bounds__(256)
void asum_part_kernel(const float* __restrict__ t1, const float* __restrict__ qp,
                      float* __restrict__ part)
{
    int blk = blockIdx.x;
    int lc = blk >> 4, b = (blk >> 2) & 3, ec = blk & 3;
    int e = ec * 256 + threadIdx.x;
    float acc = 0.f;
#pragma unroll 4
    for (int l = lc * 32; l < lc * 32 + 32; l++) {
        long idx = ((long)(l * 4 + b)) * 1024 + e;
        acc += t1[idx] + qp[idx];
    }
    part[(lc * 4 + b) * 1024 + e] = acc;
}

__global__ __launch_bounds__(256)
void asum_reduce_kernel(const float* __restrict__ part, float* __restrict__ asum)
{
    int b = blockIdx.x >> 2, ec = blockIdx.x & 3;
    int e = ec * 256 + threadIdx.x;
    float acc = 0.f;
#pragma unroll
    for (int lc = 0; lc < 16; lc++) acc += part[(lc * 4 + b) * 1024 + e];
    asum[b * 1024 + e] = acc;
}

// ---------------------------------------------------------------------------
// qsum[b,o] = sum_e cq_w[o,e]*asum[b,e] + 512*cq_b[o]
// ---------------------------------------------------------------------------
__global__ __launch_bounds__(256)
void qsum_kernel(const float* __restrict__ cqw, const float* __restrict__ cqb,
                 const float* __restrict__ asum, float* __restrict__ qsum)
{
    int o = blockIdx.x * 4 + (threadIdx.x >> 6);
    int lane = threadIdx.x & 63;
    float a0 = 0, a1 = 0, a2 = 0, a3 = 0;
    for (int j = 0; j < 16; j++) {
        int e = lane + j * 64;
        float wv = cqw[(long)o * 1024 + e];
        a0 += wv * asum[e];
        a1 += wv * asum[1024 + e];
        a2 += wv * asum[2048 + e];
        a3 += wv * asum[3072 + e];
    }
    for (int t = 32; t; t >>= 1) {
        a0 += __shfl_xor(a0, t); a1 += __shfl_xor(a1, t);
        a2 += __shfl_xor(a2, t); a3 += __shfl_xor(a3, t);
    }
    if (!lane) {
        float bb = 512.f * cqb[o];
        qsum[o] = a0 + bb; qsum[1024 + o] = a1 + bb;
        qsum[2048 + o] = a2 + bb; qsum[3072 + o] = a3 + bb;
    }
}

// ---------------------------------------------------------------------------
// cross stage A: s1[bh][m]
// ---------------------------------------------------------------------------
__global__ __launch_bounds__(256)
void s1_kernel(const float* __restrict__ kc, const float* __restrict__ qsum,
               float* __restrict__ s1)
{
    int bh = blockIdx.x, b = bh >> 4, h = bh & 15;
    int m = blockIdx.y * 256 + threadIdx.x;
    __shared__ float qd[64];
    if (threadIdx.x < 64) qd[threadIdx.x] = qsum[b * 1024 + threadIdx.x * 16 + h];
    __syncthreads();
    const float* kcb = kc + (long)b * 2048 * 1024 + (long)h * 2048 + m;
    float acc = 0.f;
#pragma unroll 8
    for (int d = 0; d < 64; d++) acc += qd[d] * kcb[(long)d * 16 * 2048];
    s1[(long)bh * 2048 + m] = acc * 0.125f;
}

// ---------------------------------------------------------------------------
// cross stage B: per (b,h,n) row max & expsum
// ---------------------------------------------------------------------------
__global__ __launch_bounds__(256)
void bsum_kernel(const float* __restrict__ kc, const float* __restrict__ s1,
                 float* __restrict__ rmax, float* __restrict__ rsum)
{
    int bh = blockIdx.x >> 6, n = blockIdx.x & 63;
    int b = bh >> 4, h = bh & 15;
    int tid = threadIdx.x, lane = tid & 63, w = tid >> 6;
    const float* row = kc + (long)b * 2048 * 1024 + (long)(n * 16 + h) * 2048;
    const float* s1r = s1 + (long)bh * 2048;
    float t[8];
    float mx = -1e30f;
#pragma unroll
    for (int i = 0; i < 8; i++) {
        int m = tid + i * 256;
        t[i] = row[m] * s1r[m];
        mx = fmaxf(mx, t[i]);
    }
    __shared__ float redm[4], reds[4];
    for (int o = 32; o; o >>= 1) mx = fmaxf(mx, __shfl_xor(mx, o));
    if (!lane) redm[w] = mx;
    __syncthreads();
    mx = fmaxf(fmaxf(redm[0], redm[1]), fmaxf(redm[2], redm[3]));
    float s = 0.f;
#pragma unroll
    for (int i = 0; i < 8; i++) s += __expf(t[i] - mx);
    for (int o = 32; o; o >>= 1) s += __shfl_xor(s, o);
    if (!lane) reds[w] = s;
    __syncthreads();
    if (!tid) {
        rmax[bh * 64 + n] = mx;
        rsum[bh * 64 + n] = reds[0] + reds[1] + reds[2] + reds[3];
    }
}

// ---------------------------------------------------------------------------
// cross stage C: wpr[bh][m]
// ---------------------------------------------------------------------------
__global__ __launch_bounds__(256)
void wpr_kernel(const float* __restrict__ kc, const float* __restrict__ s1,
                const float* __restrict__ rmax, const float* __restrict__ rsum,
                const float* __restrict__ dw, float* __restrict__ wpr)
{
    int bh = blockIdx.x, b = bh >> 4, h = bh & 15;
    int m = blockIdx.y * 256 + threadIdx.x;
    __shared__ float cf[64], cm[64];
    if (threadIdx.x < 64) {
        cf[threadIdx.x] = dw[threadIdx.x] / rsum[bh * 64 + threadIdx.x];
        cm[threadIdx.x] = rmax[bh * 64 + threadIdx.x];
    }
    __syncthreads();
    float s1v = s1[(long)bh * 2048 + m];
    const float* kcb = kc + (long)b * 2048 * 1024 + (long)h * 2048 + m;
    float acc = 0.f;
#pragma unroll 8
    for (int n = 0; n < 64; n++)
        acc += cf[n] * __expf(kcb[(long)n * 16 * 2048] * s1v - cm[n]);
    wpr[(long)bh * 2048 + m] = acc;
}

// ---------------------------------------------------------------------------
// cross stage D: outs[b, d*16+h] = sum_m wpr[bh][m]*vc[b, d*16+h, m] + db
// ---------------------------------------------------------------------------
__global__ __launch_bounds__(256)
void cout_kernel(const bf16* __restrict__ vc, const float* __restrict__ wpr,
                 const float* __restrict__ db, float* __restrict__ outs)
{
    int bh = blockIdx.x >> 2, dg = blockIdx.x & 3;
    int b = bh >> 4, h = bh & 15;
    int tid = threadIdx.x, lane = tid & 63, w = tid >> 6;
    __shared__ float lwpr[2048];
#pragma unroll
    for (int i = 0; i < 8; i++) lwpr[tid + i * 256] = wpr[(long)bh * 2048 + tid + i * 256];
    __syncthreads();
#pragma unroll
    for (int dd = 0; dd < 4; dd++) {
        int d = dg * 16 + w * 4 + dd;
        int o = d * 16 + h;
        const bf16* vrow = vc + (long)b * 2048 * 1024 + (long)o * 2048;
        float acc = 0.f;
#pragma unroll
        for (int j = 0; j < 4; j++) {
            int m = j * 512 + lane * 8;
            short8 vv = *(const short8*)&vrow[m];
#pragma unroll
            for (int k = 0; k < 8; k++) {
                bf16 bb = __builtin_bit_cast(bf16, (unsigned short)vv[k]);
                acc += lwpr[m + k] * b2f(bb);
            }
        }
        for (int t2 = 32; t2; t2 >>= 1) acc += __shfl_xor(acc, t2);
        if (!lane) outs[b * 1024 + o] = acc + db[0];
    }
}

// ---------------------------------------------------------------------------
extern "C" void kernel_launch(void* const* d_in, const int* in_sizes, int n_in,
                              void* d_out, int out_size, void* d_ws, size_t ws_size,
                              hipStream_t stream)
{
    const float* tgt  = (const float*)d_in[0];
    const float* mem  = (const float*)d_in[1];
    const float* pos  = (const float*)d_in[2];
    const float* qp   = (const float*)d_in[3];
    const float* ipw  = (const float*)d_in[4];
    const float* ipb  = (const float*)d_in[5];
    const float* outw = (const float*)d_in[6];
    const float* outb = (const float*)d_in[7];
    const float* cqw  = (const float*)d_in[8];
    const float* cqb  = (const float*)d_in[9];
    const float* ckw  = (const float*)d_in[10];
    const float* ckb  = (const float*)d_in[11];
    const float* cvw  = (const float*)d_in[12];
    const float* cvb  = (const float*)d_in[13];
    const float* dww  = (const float*)d_in[14];
    const float* dwb  = (const float*)d_in[15];
    const float* l1w  = (const float*)d_in[16];
    const float* l1b  = (const float*)d_in[17];
    const float* l2w  = (const float*)d_in[18];
    const float* l2b  = (const float*)d_in[19];
    const float* n1g  = (const float*)d_in[20];
    const float* n1b  = (const float*)d_in[21];
    const float* n2g  = (const float*)d_in[22];
    const float* n2b  = (const float*)d_in[23];
    const float* n3g  = (const float*)d_in[24];
    const float* n3b  = (const float*)d_in[25];

    char* ws = (char*)d_ws;
    auto MB = [](long x) { return x << 20; };
    bf16* w_ip    = (bf16*)(ws + MB(0));    // 6 MB  (q,k,v weights: 3072x1024)
    bf16* w_out   = (bf16*)(ws + MB(6));    // 2 MB
    bf16* w_ck    = (bf16*)(ws + MB(8));    // 2 MB
    bf16* w_cv    = (bf16*)(ws + MB(10));   // 2 MB
    bf16* w_l1    = (bf16*)(ws + MB(12));   // 4 MB
    bf16* w_l2    = (bf16*)(ws + MB(16));   // 4 MB
    bf16* qkin    = (bf16*)(ws + MB(20));   // 4 MB  bf16(tgt+qp)
    bf16* tgtb    = (bf16*)(ws + MB(24));   // 4 MB  bf16(tgt)
    bf16* memposb = (bf16*)(ws + MB(28));   // 16 MB bf16(mem+pos)
    bf16* memb    = (bf16*)(ws + MB(44));   // 16 MB bf16(mem)
    bf16* qkbuf   = (bf16*)(ws + MB(60));   // 8 MB  q|k  [2048][2048]
    bf16* vtb     = (bf16*)(ws + MB(68));   // 4 MB  vt[b][o][m]
    bf16* scores  = (bf16*)(ws + MB(72));   // 32 MB [z=64][512][512]
    float* kcf    = (float*)(ws + MB(72));  // 32 MB (reuses scores region)
    bf16* ctxb    = (bf16*)(ws + MB(104));  // 4 MB
    float* atmp   = (float*)(ws + MB(108)); // 8 MB (LN1 input)
    float* s1buf  = (float*)(ws + MB(108)); // 512 KB (after LN1)
    float* wprbuf = (float*)(ws + MB(109)); // 512 KB
    float* rmax   = (float*)(ws + MB(110));              // 16 KB
    float* rsum   = (float*)(ws + MB(110) + (64 << 10)); // 16 KB
    float* part   = (float*)(ws + MB(111)); // 256 KB
    float* tgt1   = (float*)(ws + MB(116)); // 8 MB
    float* asum   = (float*)(ws + MB(124)); // 16 KB
    float* qsum   = (float*)(ws + MB(125)); // 16 KB
    bf16* vcb     = (bf16*)(ws + MB(126));  // 16 MB [b][o][m]
    float* outs   = (float*)(ws + MB(142)); // 16 KB
    float* tgt2   = (float*)(ws + MB(143)); // 8 MB
    bf16* tgt2b   = (bf16*)(ws + MB(151));  // 4 MB
    bf16* ff1b    = (bf16*)(ws + MB(155));  // 8 MB
    float* ff2    = (float*)(ws + MB(163)); // 8 MB  -> total 171 MB

    const int BIGZ = 1000000, BIGN = 1 << 30;

    // --- prepass: dedup f32->bf16 conversions (each input read once) ---
    Cvt2Args ca{};
    ca.s[0] = {ipw,  nullptr, w_ip,    nullptr, 1536};
    ca.s[1] = {outw, nullptr, w_out,   nullptr, 512};
    ca.s[2] = {ckw,  nullptr, w_ck,    nullptr, 512};
    ca.s[3] = {cvw,  nullptr, w_cv,    nullptr, 512};
    ca.s[4] = {l1w,  nullptr, w_l1,    nullptr, 1024};
    ca.s[5] = {l2w,  nullptr, w_l2,    nullptr, 1024};
    ca.s[6] = {tgt,  qp,      qkin,    tgtb,    1024};
    ca.s[7] = {mem,  pos,     memposb, memb,    4096};
    cvt_kernel<<<dim3(10240, 1, 1), 256, 0, stream>>>(ca);

    // --- fused qkv projection: [2048,1024]x[1024,3072] ---
    //     cols 0..2047 -> qkbuf (A=qkin); cols 2048..3071 -> vt scatter (A=tgtb)
    gemm_nt<128, 128><<<dim3(16, 24, 1), 256, 0, stream>>>(
        qkin, w_ip, nullptr, qkbuf, ipb,
        tgtb, nullptr, vtb, nullptr,
        1024, 1024, 1024, 2048,
        0, 0, 0, 0, 0, 0, 1, BIGZ, 2048, 1.f, 1, 3);

    // --- QK^T: per z=(b*16+h): [512,64]x[64,512] * 0.125 -> scores bf16 ---
    gemm_nt<128, 128><<<dim3(4, 4, 64), 256, 0, stream>>>(
        qkbuf, qkbuf + 1024, nullptr, scores, nullptr,
        nullptr, nullptr, nullptr, nullptr,
        64, 8192, 8192, 512,
        2048, 64, 2048, 64, 4194304, 262144, 16, BIGZ, BIGN, 0.125f, 1, 1);

    softmax_self<<<dim3(8192, 1, 1), 256, 0, stream>>>(scores);

    // --- PV: per z: [512,512]x[512,64] -> ctxb ---
    gemm_nt<128, 64><<<dim3(4, 1, 64), 256, 0, stream>>>(
        scores, vtb, nullptr, ctxb, nullptr,
        nullptr, nullptr, nullptr, nullptr,
        512, 512, 512, 4096,
        4194304, 262144, 524288, 32768, 1024, 64, 16, BIGZ, BIGN, 1.f, 1, 1);

    // --- out projection -> atmp f32 (64x128 tile: 256 blocks) ---
    gemm_nt<64, 128><<<dim3(32, 8, 1), 256, 0, stream>>>(
        ctxb, w_out, atmp, nullptr, outb,
        nullptr, nullptr, nullptr, nullptr,
        1024, 1024, 1024, 1024,
        0, 0, 0, 0, 0, 0, 1, BIGZ, BIGN, 1.f, 0, 0);

    // --- LN1 ---
    ln_kernel<<<dim3(2048, 1, 1), 256, 0, stream>>>(atmp, tgt, nullptr, n1g, n1b, tgt1, nullptr);

    // --- qc path ---
    asum_part_kernel<<<dim3(256, 1, 1), 256, 0, stream>>>(tgt1, qp, part);
    asum_reduce_kernel<<<dim3(16, 1, 1), 256, 0, stream>>>(part, asum);
    qsum_kernel<<<dim3(256, 1, 1), 256, 0, stream>>>(cqw, cqb, asum, qsum);

    // --- fused kc+vc: z=0..3 kc (f32 out), z=4..7 vc (bf16 out) ---
    gemm_nt<128, 128><<<dim3(8, 16, 8), 256, 0, stream>>>(
        w_ck, memposb, kcf, vcb, ckb,
        w_cv, memb, nullptr, cvb,
        1024, 1024, 4096, 2048,
        0, 0, 1024, 0, 2097152, 0, 1, 4, BIGN, 1.f, 0, 1);

    // --- cross attention stages ---
    s1_kernel<<<dim3(64, 8, 1), 256, 0, stream>>>(kcf, qsum, s1buf);
    bsum_kernel<<<dim3(4096, 1, 1), 256, 0, stream>>>(kcf, s1buf, rmax, rsum);
    wpr_kernel<<<dim3(64, 8, 1), 256, 0, stream>>>(kcf, s1buf, rmax, rsum, dww, wprbuf);
    cout_kernel<<<dim3(256, 1, 1), 256, 0, stream>>>(vcb, wprbuf, dwb, outs);

    // --- LN2 ---
    ln_kernel<<<dim3(2048, 1, 1), 256, 0, stream>>>(tgt1, nullptr, outs, n2g, n2b, tgt2, tgt2b);

    // --- FFN ---
    gemm_nt<128, 128><<<dim3(16, 16, 1), 256, 0, stream>>>(
        tgt2b, w_l1, nullptr, ff1b, l1b,
        nullptr, nullptr, nullptr, nullptr,
        1024, 1024, 1024, 2048,
        0, 0, 0, 0, 0, 0, 1, BIGZ, BIGN, 1.f, 2, 2);

    gemm_nt<64, 128><<<dim3(32, 8, 1), 256, 0, stream>>>(
        ff1b, w_l2, ff2, nullptr, l2b,
        nullptr, nullptr, nullptr, nullptr,
        2048, 2048, 2048, 1024,
        0, 0, 0, 0, 0, 0, 1, BIGZ, BIGN, 1.f, 0, 0);

    // --- LN3 -> d_out ---
    ln_kernel<<<dim3(2048, 1, 1), 256, 0, stream>>>(ff2, tgt2, nullptr, n3g, n3b, (float*)d_out, nullptr);
}